// Round 3
// baseline (230.276 us; speedup 1.0000x reference)
//
#include <hip/hip_runtime.h>

// Problem constants
#define BATCH 4
#define SEQ   2048
#define DIM   1024
#define MTOT  (BATCH * SEQ)   // 8192
#define BK    32              // k-tile depth for the legacy 128x128 core

typedef __bf16 bf16x8 __attribute__((ext_vector_type(8)));
typedef __bf16 bf16x4 __attribute__((ext_vector_type(4)));
typedef float  f32x4  __attribute__((ext_vector_type(4)));

// Async global->LDS, 16B per lane.
__device__ __forceinline__ void gl_lds16(const __bf16* g, __bf16* l) {
    __builtin_amdgcn_global_load_lds(
        (const __attribute__((address_space(1))) void*)g,
        (__attribute__((address_space(3))) void*)l,
        16, 0, 0);
}

// ---------------------------------------------------------------------------
// K0: fused fp32 -> bf16 conversion for x, Wq, Wk, Wv in ONE launch.
// Blocks 5632..5639 zero the row-sum accumulator (8192 f32).
__global__ __launch_bounds__(256) void cvt_all_kernel(
    const float* __restrict__ x,  const float* __restrict__ w0,
    const float* __restrict__ w1, const float* __restrict__ w2,
    __bf16* __restrict__ xd, __bf16* __restrict__ d0,
    __bf16* __restrict__ d1, __bf16* __restrict__ d2,
    float* __restrict__ sums)
{
    const int bid = blockIdx.x;
    if (bid >= 5632) {
        const int i = ((bid - 5632) * 256 + threadIdx.x) * 4;
        *(float4*)(sums + i) = (float4){0.f, 0.f, 0.f, 0.f};
        return;
    }
    const float* s;
    __bf16* d;
    int base;
    if (bid < 4096)      { s = x;  d = xd; base = bid; }
    else if (bid < 4608) { s = w0; d = d0; base = bid - 4096; }
    else if (bid < 5120) { s = w1; d = d1; base = bid - 4608; }
    else                 { s = w2; d = d2; base = bid - 5120; }
    const int i = (base * 256 + threadIdx.x) * 8;
    const float4 a = *(const float4*)(s + i);
    const float4 b = *(const float4*)(s + i + 4);
    bf16x8 o;
    o[0] = (__bf16)a.x; o[1] = (__bf16)a.y; o[2] = (__bf16)a.z; o[3] = (__bf16)a.w;
    o[4] = (__bf16)b.x; o[5] = (__bf16)b.y; o[6] = (__bf16)b.z; o[7] = (__bf16)b.w;
    *(bf16x8*)(d + i) = o;
}

// ---------------------------------------------------------------------------
// Legacy 128x128 bf16 GEMM core (m97 structure) — still used by scores/pv.
__device__ __forceinline__ void gemm_core(
    const __bf16* __restrict__ A, size_t lda,
    const __bf16* __restrict__ Bm, size_t ldb,
    int m0, int n0, int kTiles,
    __bf16* lA, __bf16* lB,
    f32x4 (&acc)[4][4])
{
    const int tid  = threadIdx.x;
    const int lane = tid & 63;
    const int wave = tid >> 6;
    const int wm = (wave >> 1) << 6;
    const int wn = (wave & 1) << 6;

#pragma unroll
    for (int i = 0; i < 4; ++i)
#pragma unroll
        for (int j = 0; j < 4; ++j)
            acc[i][j] = (f32x4){0.f, 0.f, 0.f, 0.f};

    for (int kt = 0; kt < kTiles; ++kt) {
        const int k0 = kt << 5;
        __syncthreads();
#pragma unroll
        for (int it = 0; it < 2; ++it) {
            const int f   = tid + (it << 8);
            const int row = f >> 2;
            const int col = (f & 3) << 3;
            gl_lds16(A  + (size_t)(m0 + row) * lda + (size_t)(k0 + col), lA + f * 8);
            gl_lds16(Bm + (size_t)(n0 + row) * ldb + (size_t)(k0 + col), lB + f * 8);
        }
        __syncthreads();

        bf16x8 af[4], bfr[4];
#pragma unroll
        for (int i = 0; i < 4; ++i) {
            af[i]  = *(const bf16x8*)(lA + (size_t)(wm + i * 16 + (lane & 15)) * BK + ((lane >> 4) << 3));
            bfr[i] = *(const bf16x8*)(lB + (size_t)(wn + i * 16 + (lane & 15)) * BK + ((lane >> 4) << 3));
        }
#pragma unroll
        for (int i = 0; i < 4; ++i)
#pragma unroll
            for (int j = 0; j < 4; ++j)
                acc[i][j] = __builtin_amdgcn_mfma_f32_16x16x32_bf16(af[i], bfr[j], acc[i][j], 0, 0, 0);
    }
}

// Epilogue for the legacy core (scores/pv): C-tile -> LDS scratch -> coalesced
// bf16x8 stores. expMask: store exp(val*scale), causal-masked on diag tiles.
// sums!=nullptr: accumulate per-row sums of the STORED (bf16-rounded) values
// via 16-lane shfl reduce + one f32 atomicAdd per row per wave.
__device__ __forceinline__ void store_tile_bf16(
    f32x4 (&acc)[4][4], __bf16* scratch, bool transpose, float scale,
    __bf16* dst, size_t ldo, size_t r0, size_t c0,
    bool expMask = false, bool diag = false, float* sums = nullptr)
{
    const int tid  = threadIdx.x;
    const int lane = tid & 63;
    const int wave = tid >> 6;
    const int wm = (wave >> 1) << 6, wn = (wave & 1) << 6;
    const int quad = lane >> 4;
    const int ln15 = lane & 15;

#pragma unroll
    for (int p = 0; p < 4; ++p) {
        __syncthreads();
        if (!transpose) {
            if (wm == ((p >> 1) << 6)) {
#pragma unroll
                for (int ih = 0; ih < 2; ++ih) {
                    const int i = ((p & 1) << 1) + ih;
                    const int lr = ih * 16 + quad * 4;
#pragma unroll
                    for (int r = 0; r < 4; ++r) {
                        const int lm = wm + ((p & 1) << 5) + lr + r;
                        float ps = 0.f;
#pragma unroll
                        for (int j = 0; j < 4; ++j) {
                            const int ln = wn + j * 16 + ln15;
                            float v = acc[i][j][r] * scale;
                            if (expMask) {
                                v = (!diag || ln <= lm) ? __expf(v) : 0.f;
                            }
                            const __bf16 vb = (__bf16)v;
                            scratch[(lr + r) * 136 + ln] = vb;
                            ps += (float)vb;
                        }
                        if (sums) {
#pragma unroll
                            for (int off = 1; off < 16; off <<= 1)
                                ps += __shfl_xor(ps, off);
                            if (ln15 == 0)
                                atomicAdd(&sums[r0 + (p << 5) + lr + r], ps);
                        }
                    }
                }
            }
        } else {
            if (wn == ((p >> 1) << 6)) {
#pragma unroll
                for (int jh = 0; jh < 2; ++jh) {
                    const int j = ((p & 1) << 1) + jh;
                    const int lr = jh * 16 + ln15;
#pragma unroll
                    for (int i = 0; i < 4; ++i)
#pragma unroll
                        for (int r = 0; r < 4; ++r)
                            scratch[lr * 136 + wm + i * 16 + quad * 4 + r] =
                                (__bf16)(acc[i][j][r] * scale);
                }
            }
        }
        __syncthreads();
#pragma unroll
        for (int it = 0; it < 2; ++it) {
            const int g   = tid + (it << 8);
            const int row = g >> 4;
            const int col = (g & 15) << 3;
            *(bf16x8*)(dst + (r0 + p * 32 + row) * ldo + c0 + col) =
                *(const bf16x8*)(scratch + row * 136 + col);
        }
    }
}

// ---------------------------------------------------------------------------
// K1: QKV — 256 blocks (1 exact dispatch round), each doing 3 sequential
// 256x128 units sharing the same A-panel (m-rows). Per unit: the round-2
// proven 4-quadrant BK=64 pipeline transplanted to 256x128:
//   - 8 waves 2M x 4N; per-wave 128x32 GAPPED (rows wm*64+[0,64) U 128+...,
//     cols wn*16+[0,16) U 64+...), acc[8][2] = 64 VGPR.
//   - Quadrants (A0,B0)->(A0,B1)->(A1,B1)->(A1,B0) with B0 frags held in
//     registers across the tile; q3 has no ds_read.
//   - Rotation swizzle (phys chunk = (log + row&7)&7), inverse on the
//     global_load_lds source, forward on ds_read (both-sides rule).
//   - Ledger (per gl_lds16 inst): q0: SB1(T+1)[1]; q1: SA1(T+1)[2];
//     q2: SA0(T+2)[2]; q3: SB0(T+2)[1] + vmcnt(3). Slot deaths: A0 after q1,
//     B0 after q0, B1 after q1, A1 after q2 — every stage >=2 barriers after
//     the last read of the slot it overwrites.
//   - LDS 96 KiB: dbuf x (A 256x64 + B 128x64); 1 block/CU, 2 waves/SIMD.
__global__ __launch_bounds__(512, 2) void qkv_kernel(
    const __bf16* __restrict__ x,
    const __bf16* __restrict__ Wq,
    const __bf16* __restrict__ Wk,
    const __bf16* __restrict__ Wv,
    __bf16* __restrict__ Q, __bf16* __restrict__ Kb, __bf16* __restrict__ Vt)
{
    __shared__ __bf16 smem[49152];   // 96 KiB

    const int L  = blockIdx.x;
    const int g  = (L & 7) * 32 + (L >> 3);   // bijective XCD swizzle (256=8*32)
    const int m0 = (g >> 3) << 8;             // 32 m-panels of 256 rows
    const int B3 = g & 7;                     // unit-triple within the panel

    const int tid  = threadIdx.x;
    const int lane = tid & 63;
    const int ln15 = lane & 15;
    const int quad = lane >> 4;
    const int wave = tid >> 6;
    const int wm   = wave >> 2;        // 0..1 (M)
    const int wn   = wave & 3;         // 0..3 (N)

    // Staging: LDS dest linear; global source column carries the INVERSE
    // rotation so the rotated ds_read returns the right element.
    const int r0  = tid >> 3;                                   // dest row 0..63
    const int cst = ((((tid & 7) + 8) - (r0 & 7)) & 7) << 3;    // element col
    // Fragment read offsets: phys col = (ksub*32 + quad*8 + (row&7)*8) & 63.
    const int cq  = (((quad << 3) + ((ln15 & 7) << 3)) & 63);

    int aoff[4];
#pragma unroll
    for (int i = 0; i < 4; ++i) aoff[i] = ((wm << 6) + i * 16 + ln15) * 64 + cq;
    const int boff = (wn * 16 + ln15) * 64 + cq;

    const __bf16* Ab = x + (size_t)m0 * DIM;
    const int nt = DIM / 64;   // 16 K-tiles

    for (int uu = 0; uu < 3; ++uu) {
        const int u  = B3 * 3 + uu;
        const int z  = u >> 3;             // 0=Q, 1=K, 2=V
        const int nh = u & 7;
        const int n0 = nh << 7;
        const __bf16* W  = (z == 0) ? Wq : (z == 1) ? Wk : Wv;
        const __bf16* Bb = W + (size_t)n0 * DIM;

        f32x4 acc[8][2];
#pragma unroll
        for (int i = 0; i < 8; ++i)
#pragma unroll
            for (int j = 0; j < 2; ++j) acc[i][j] = (f32x4){0.f, 0.f, 0.f, 0.f};

        // LDS layout (elems): buf*24576 + [A: h*8192 + row*64+col]
        //                               [B: 16384 + h*4096 + row*64+col]
#define SA(h, t) do {                                                         \
    const __bf16* gs_ = Ab + (size_t)((h) * 128 + r0) * DIM + ((t) << 6) + cst; \
    __bf16* ls_ = smem + (((t) & 1) * 24576 + (h) * 8192) + tid * 8;          \
    gl_lds16(gs_, ls_);                                                       \
    gl_lds16(gs_ + (size_t)64 * DIM, ls_ + 4096); } while (0)
#define SB(h, t) do {                                                         \
    const __bf16* gs_ = Bb + (size_t)((h) * 64 + r0) * DIM + ((t) << 6) + cst; \
    __bf16* ls_ = smem + (((t) & 1) * 24576 + 16384 + (h) * 4096) + tid * 8;  \
    gl_lds16(gs_, ls_); } while (0)

        bf16x8 aF[4][2], bF[2][2];   // bF[set][ksub]; set0 = B-half0 persists
#define LOAD_A(h) do { const __bf16* p_ = smem + cb_ * 24576 + (h) * 8192;    \
    _Pragma("unroll") for (int i_ = 0; i_ < 4; ++i_) {                        \
        aF[i_][0] = *(const bf16x8*)(p_ + aoff[i_]);                          \
        aF[i_][1] = *(const bf16x8*)(p_ + (aoff[i_] ^ 32)); } } while (0)
#define LOAD_B(s, h) do {                                                     \
    const __bf16* p_ = smem + cb_ * 24576 + 16384 + (h) * 4096;               \
    bF[s][0] = *(const bf16x8*)(p_ + boff);                                   \
    bF[s][1] = *(const bf16x8*)(p_ + (boff ^ 32)); } while (0)
#define MFMA_Q(mh, nhb, s) do {                                               \
    __builtin_amdgcn_s_setprio(1);                                            \
    _Pragma("unroll") for (int i_ = 0; i_ < 4; ++i_) {                        \
        acc[(mh)*4+i_][nhb] = __builtin_amdgcn_mfma_f32_16x16x32_bf16(        \
            aF[i_][0], bF[s][0], acc[(mh)*4+i_][nhb], 0, 0, 0);               \
        acc[(mh)*4+i_][nhb] = __builtin_amdgcn_mfma_f32_16x16x32_bf16(        \
            aF[i_][1], bF[s][1], acc[(mh)*4+i_][nhb], 0, 0, 0); }             \
    __builtin_amdgcn_s_setprio(0); } while (0)

        // Prologue (FIFO): A0(0)[2], B0(0)[1], B1(0)[1], A1(0)[2], A0(1)[2], B0(1)[1]
        SA(0, 0);
        SB(0, 0);
        SB(1, 0);
        SA(1, 0);
        SA(0, 1);
        SB(0, 1);
        asm volatile("s_waitcnt vmcnt(3)" ::: "memory");   // tile 0 landed
        __builtin_amdgcn_s_barrier();

        for (int T = 0; T < nt; ++T) {
            const int cb_ = T & 1;
            // q0: (A0,B0->set0); stage B1(T+1) [B1(T-1) dead after q1(T-1)]
            LOAD_A(0); LOAD_B(0, 0);
            if (T + 1 < nt) SB(1, T + 1);
            __builtin_amdgcn_s_barrier();
            MFMA_Q(0, 0, 0);
            __builtin_amdgcn_s_barrier();
            // q1: (A0,B1->set1); stage A1(T+1) [A1(T-1) dead after q2(T-1)]
            LOAD_B(1, 1);
            if (T + 1 < nt) SA(1, T + 1);
            __builtin_amdgcn_s_barrier();
            MFMA_Q(0, 1, 1);
            __builtin_amdgcn_s_barrier();
            // q2: (A1,B1 regs); stage A0(T+2) [A0(T) dead after q1(T)]
            LOAD_A(1);
            if (T + 2 < nt) SA(0, T + 2);
            __builtin_amdgcn_s_barrier();
            MFMA_Q(1, 1, 1);
            __builtin_amdgcn_s_barrier();
            // q3: (A1,B0 regs) — no ds_read; stage B0(T+2); counted wait
            if (T + 2 < nt) {
                SB(0, T + 2);
                asm volatile("s_waitcnt vmcnt(3)" ::: "memory");  // T+1 landed
            } else if (T + 1 < nt) {
                asm volatile("s_waitcnt vmcnt(0)" ::: "memory");  // tail drain
            }
            __builtin_amdgcn_s_barrier();
            MFMA_Q(1, 0, 0);
            __builtin_amdgcn_s_barrier();
        }
#undef SA
#undef SB
#undef LOAD_A
#undef LOAD_B
#undef MFMA_Q

        // ---------------- epilogue ----------------
        __syncthreads();
        __bf16* scratch = smem;

        if (z < 2) {
            __bf16* dst = (z == 0) ? Q : Kb;
#pragma unroll
            for (int h = 0; h < 2; ++h) {     // slab: C rows h*128..h*128+127
#pragma unroll
                for (int i = 0; i < 4; ++i) {
                    const int lr = wm * 64 + i * 16 + quad * 4;
#pragma unroll
                    for (int nhb = 0; nhb < 2; ++nhb) {
                        const int lc = nhb * 64 + wn * 16 + ln15;
#pragma unroll
                        for (int r = 0; r < 4; ++r)
                            scratch[(lr + r) * 136 + lc] = (__bf16)acc[h * 4 + i][nhb][r];
                    }
                }
                __syncthreads();
#pragma unroll
                for (int it = 0; it < 4; ++it) {
                    const int f = tid + (it << 9);
                    const int row = f >> 4, col = (f & 15) << 3;
                    *(bf16x8*)(dst + (size_t)(m0 + h * 128 + row) * DIM + n0 + col) =
                        *(const bf16x8*)(scratch + row * 136 + col);
                }
                __syncthreads();
            }
        } else {
            // V transposed: Vt[b][d][s]; scratch[d 128][s 256], stride 264
            const size_t b  = (size_t)(m0 >> 11);
            const int  ms0  = m0 & (SEQ - 1);
            __bf16* dst = Vt + b * (size_t)DIM * SEQ;
#pragma unroll
            for (int mh = 0; mh < 2; ++mh)
#pragma unroll
                for (int i = 0; i < 4; ++i) {
                    const int sl = mh * 128 + wm * 64 + i * 16 + quad * 4;
#pragma unroll
                    for (int nhb = 0; nhb < 2; ++nhb) {
                        const int dl = nhb * 64 + wn * 16 + ln15;
                        bf16x4 v;
#pragma unroll
                        for (int r = 0; r < 4; ++r) v[r] = (__bf16)acc[mh * 4 + i][nhb][r];
                        *(bf16x4*)(scratch + dl * 264 + sl) = v;
                    }
                }
            __syncthreads();
#pragma unroll
            for (int it = 0; it < 8; ++it) {
                const int f = tid + (it << 9);
                const int row = f >> 5, blk = f & 31;
                *(bf16x8*)(dst + (size_t)(n0 + row) * SEQ + ms0 + blk * 8) =
                    *(const bf16x8*)(scratch + row * 264 + blk * 8);
            }
            __syncthreads();
        }
    }
}

// ---------------------------------------------------------------------------
// K2: Sc[b] = exp( Q[b]·K[b]^T / 32 ), UNNORMALIZED, causal-masked on the
// diagonal tile; also accumulates per-row sums (fused rowsum). Tri-packed
// 544 blocks; XCD swizzle.
__global__ __launch_bounds__(256) void scores_kernel(
    const __bf16* __restrict__ Q, const __bf16* __restrict__ Kb,
    __bf16* __restrict__ Sc, float* __restrict__ sums)
{
    const int L = blockIdx.x;
    const int g = (L & 7) * 68 + (L >> 3);   // 0..543
    const int b = g / 136;
    const int t = g - b * 136;
    int i = (int)((sqrtf(8.f * t + 1.f) - 1.f) * 0.5f);
    while ((i + 1) * (i + 2) / 2 <= t) ++i;
    while (i * (i + 1) / 2 > t) --i;
    const int j = t - i * (i + 1) / 2;

    __shared__ __bf16 smem[8192];
    __bf16* lA = smem;
    __bf16* lB = smem + 128 * BK;
    const __bf16* A  = Q  + (size_t)b * SEQ * DIM;
    const __bf16* Bm = Kb + (size_t)b * SEQ * DIM;

    f32x4 acc[4][4];
    gemm_core(A, DIM, Bm, DIM, i << 7, j << 7, DIM / BK, lA, lB, acc);

    store_tile_bf16(acc, smem, false, 0.03125f,   // 1/sqrt(1024)
                    Sc + (size_t)b * SEQ * SEQ, SEQ,
                    (size_t)(i << 7), (size_t)(j << 7),
                    /*expMask=*/true, /*diag=*/(i == j),
                    sums + (size_t)b * SEQ);
}

// ---------------------------------------------------------------------------
// K4: O[b] = (P'[b] @ V[b]) / rowsum, k-tiles to the causal diagonal, fp32 out.
__global__ __launch_bounds__(256) void pv_kernel(
    const __bf16* __restrict__ P, const __bf16* __restrict__ Vt,
    const float* __restrict__ sums, float* __restrict__ out)
{
    const int L = blockIdx.x;
    const int c = L & 7;
    const int k = L >> 3;                 // 0..63
    const int b = c >> 1;
    const int i = 15 - (c & 1) - ((k >> 3) << 1);   // 15,13,..,1 or 14,12,..,0
    const int x = k & 7;

    __shared__ __bf16 smem[8192];
    __bf16* lA = smem;
    __bf16* lB = smem + 128 * BK;
    const __bf16* A  = P  + (size_t)b * SEQ * SEQ;
    const __bf16* Bm = Vt + (size_t)b * DIM * SEQ;

    f32x4 acc[4][4];
    gemm_core(A, SEQ, Bm, SEQ, i << 7, x << 7, (i + 1) * (128 / BK), lA, lB, acc);

    const int lane = threadIdx.x & 63;
    const int wave = threadIdx.x >> 6;
    const int wm = (wave >> 1) << 6, wn = (wave & 1) << 6;
#pragma unroll
    for (int ii = 0; ii < 4; ++ii)
#pragma unroll
        for (int jj = 0; jj < 4; ++jj)
#pragma unroll
            for (int r = 0; r < 4; ++r) {
                const int m = (i << 7) + wm + ii * 16 + ((lane >> 4) << 2) + r;
                const int n = (x << 7) + wn + jj * 16 + (lane & 15);
                out[((size_t)b * SEQ + m) * DIM + n] =
                    acc[ii][jj][r] / sums[(b << 11) + m];
            }
}

// ---------------------------------------------------------------------------
extern "C" void kernel_launch(void* const* d_in, const int* in_sizes, int n_in,
                              void* d_out, int out_size, void* d_ws, size_t ws_size,
                              hipStream_t stream) {
    const float* x  = (const float*)d_in[0];   // fp32 per reference
    const float* Wq = (const float*)d_in[1];
    const float* Wk = (const float*)d_in[2];
    const float* Wv = (const float*)d_in[3];
    float* out = (float*)d_out;                // fp32 output (reference dtype)

    char* ws = (char*)d_ws;
    __bf16* Q  = (__bf16*)(ws);                       // 16 MB
    __bf16* Kb = (__bf16*)(ws + (16ull << 20));       // 16 MB
    __bf16* Vt = (__bf16*)(ws + (32ull << 20));       // 16 MB
    __bf16* Sc = (__bf16*)(ws + (48ull << 20));       // 32 MB bf16 exp-scores
    __bf16* Wqb = (__bf16*)(ws + (80ull << 20));      // 2 MB
    __bf16* Wkb = (__bf16*)(ws + (82ull << 20));      // 2 MB
    __bf16* Wvb = (__bf16*)(ws + (84ull << 20));      // 2 MB
    float*  sums = (float*)(ws + (86ull << 20));      // 32 KB row sums
    // bf16 x copy lives in d_out (32 MB fp32): dead before pv writes out.
    __bf16* xb  = (__bf16*)d_out;                     // 16 MB

    cvt_all_kernel<<<dim3(5640), 256, 0, stream>>>(x, Wq, Wk, Wv, xb, Wqb, Wkb, Wvb, sums);

    qkv_kernel    <<<dim3(256),  512, 0, stream>>>(xb, Wqb, Wkb, Wvb, Q, Kb, Vt);
    scores_kernel <<<dim3(544),  256, 0, stream>>>(Q, Kb, Sc, sums);
    pv_kernel     <<<dim3(512),  256, 0, stream>>>(Sc, Vt, sums, out);
}